// Round 4
// baseline (213.955 us; speedup 1.0000x reference)
//
#include <hip/hip_runtime.h>
#include <hip/hip_bf16.h>

#define LOG2E 1.4426950408889634f

// ---- native transcendentals (VOP1, proven correct in rounds 1-2) ----
__device__ __forceinline__ float fexp2(float x) {
#if __has_builtin(__builtin_amdgcn_exp2f)
    return __builtin_amdgcn_exp2f(x);
#else
    float r; asm("v_exp_f32 %0, %1" : "=v"(r) : "v"(x)); return r;
#endif
}
__device__ __forceinline__ float frcp(float x) {
#if __has_builtin(__builtin_amdgcn_rcpf)
    return __builtin_amdgcn_rcpf(x);
#else
    float r; asm("v_rcp_f32 %0, %1" : "=v"(r) : "v"(x)); return r;
#endif
}

// Quad-lane XOR shuffle via DPP quad_perm (full-rate VALU).
template<int MASK>
__device__ __forceinline__ float hxor(float v) {
#if __has_builtin(__builtin_amdgcn_update_dpp)
    constexpr int ctrl = (0 ^ MASK) | ((1 ^ MASK) << 2) | ((2 ^ MASK) << 4) | ((3 ^ MASK) << 6);
    return __int_as_float(__builtin_amdgcn_update_dpp(
        0, __float_as_int(v), ctrl, 0xf, 0xf, true));
#else
    return __shfl_xor(v, MASK, 64);
#endif
}

// One lane = hidden unit j of TWO batch elements (b0 = p, b1 = p + B/2),
// kept as two SCALAR chains software-pipelined half a step apart:
//   rotation per step k:  G_A(k) ; F_B(k-1) ; F_A(k) ; G_B(k)
// so every dependency has one independent phase between producer & consumer.
// Gate order (PyTorch): i,f,g,o. exp2 scales pre-folded into weights/biases.
__global__ __launch_bounds__(256, 1) void lstm_h4sp_kernel(
    const float* __restrict__ x,
    const float* __restrict__ W_ih,   // [16]
    const float* __restrict__ W_hh,   // [16][4]
    const float* __restrict__ b_ih,   // [16]
    const float* __restrict__ b_hh,   // [16]
    const float* __restrict__ fc_w,   // [4]
    const float* __restrict__ fc_b,   // [1]
    float* __restrict__ out,          // [B]
    int B, int T)
{
    const int tid  = blockIdx.x * blockDim.x + threadIdx.x;
    const int half = B >> 1;
    const int p = tid >> 2;          // batch-pair index
    const int j = tid & 3;           // hidden unit owned by this lane
    if (p >= half) return;
    const int b0 = p, b1 = p + half;

    const float si = -LOG2E;          // sigmoid: E = exp2(si*z) = e^-z
    const float sg = -2.0f * LOG2E;   // tanh:    E = exp2(sg*z) = e^-2z

    const int ri = j, rf = 4 + j, rg = 8 + j, ro = 12 + j;

    const float Ai = si * W_ih[ri], Ci = si * (b_ih[ri] + b_hh[ri]);
    const float Af = si * W_ih[rf], Cf = si * (b_ih[rf] + b_hh[rf]);
    const float Ag = sg * W_ih[rg], Cg = sg * (b_ih[rg] + b_hh[rg]);
    const float Ao = si * W_ih[ro], Co = si * (b_ih[ro] + b_hh[ro]);

    // Recurrent weights, permuted so index m pairs with h_{j^m}
    const float Wi0 = si * W_hh[ri*4 + (j^0)], Wi1 = si * W_hh[ri*4 + (j^1)];
    const float Wi2 = si * W_hh[ri*4 + (j^2)], Wi3 = si * W_hh[ri*4 + (j^3)];
    const float Wf0 = si * W_hh[rf*4 + (j^0)], Wf1 = si * W_hh[rf*4 + (j^1)];
    const float Wf2 = si * W_hh[rf*4 + (j^2)], Wf3 = si * W_hh[rf*4 + (j^3)];
    const float Wg0 = sg * W_hh[rg*4 + (j^0)], Wg1 = sg * W_hh[rg*4 + (j^1)];
    const float Wg2 = sg * W_hh[rg*4 + (j^2)], Wg3 = sg * W_hh[rg*4 + (j^3)];
    const float Wo0 = si * W_hh[ro*4 + (j^0)], Wo1 = si * W_hh[ro*4 + (j^1)];
    const float Wo2 = si * W_hh[ro*4 + (j^2)], Wo3 = si * W_hh[ro*4 + (j^3)];

    float hA = 0.0f, cA = 0.0f, hB = 0.0f, cB = 0.0f;
    float EiA, EfA, EgA, EoA;         // G_A results pending F_A
    float EiB, EfB, EgB, EoB;         // G_B results pending F_B

    // G: gate pre-activations (depth-3 tree) + 4 exps.
    auto G = [&](float h, float xv, float& Ei, float& Ef, float& Eg, float& Eo) {
        const float h1 = hxor<1>(h);
        const float h2 = hxor<2>(h);
        const float h3 = hxor<3>(h);
        const float zi = fmaf(Wi1, h1, fmaf(Wi0, h, fmaf(Ai, xv, Ci)))
                       + fmaf(Wi3, h3, Wi2 * h2);
        const float zf = fmaf(Wf1, h1, fmaf(Wf0, h, fmaf(Af, xv, Cf)))
                       + fmaf(Wf3, h3, Wf2 * h2);
        const float zg = fmaf(Wg1, h1, fmaf(Wg0, h, fmaf(Ag, xv, Cg)))
                       + fmaf(Wg3, h3, Wg2 * h2);
        const float zo = fmaf(Wo1, h1, fmaf(Wo0, h, fmaf(Ao, xv, Co)))
                       + fmaf(Wo3, h3, Wo2 * h2);
        Ei = fexp2(zi); Ef = fexp2(zf); Eg = fexp2(zg); Eo = fexp2(zo);
    };

    // F: cell + hidden tail.  E* = e^{-z} (sig) / e^{-2z} (tanh), p* = 1+E*:
    //   c' = [c*pi*pg + (1-Eg)*pf] * rcp(pf*pi*pg)
    //   h  = (1-Ec) * rcp(fma(Ec,po,po)),  Ec = exp2(sg*c')
    auto F = [&](float& h, float& c, float Ei, float Ef, float Eg, float Eo) {
        const float pi_ = 1.0f + Ei, pf_ = 1.0f + Ef;
        const float pg_ = 1.0f + Eg, po_ = 1.0f + Eo;
        const float t1  = pi_ * pg_;
        const float u   = fmaf(-Eg, pf_, pf_);      // (1-Eg)*pf
        const float num = fmaf(c, t1, u);
        const float den = t1 * pf_;
        const float r   = frcp(den);
        const float sn  = sg * num;                 // in rcp's shadow
        c = num * r;
        const float Ec  = fexp2(sn * r);            // exp2(sg*c')
        const float d2  = fmaf(Ec, po_, po_);       // po*(1+Ec)
        const float r2  = frcp(d2);
        h = fmaf(-Ec, r2, r2);                      // (1-Ec)*rcp(...)
    };

    auto GA = [&](float xv) { G(hA, xv, EiA, EfA, EgA, EoA); };
    auto GB = [&](float xv) { G(hB, xv, EiB, EfB, EgB, EoB); };
    auto FA = [&]() { F(hA, cA, EiA, EfA, EgA, EoA); };
    auto FB = [&]() { F(hB, cB, EiB, EfB, EgB, EoB); };

    // Rotation: G_A(k); F_B(k-1); F_A(k); G_B(k)
    auto ROT = [&](float xa, float xb) { GA(xa); FB(); FA(); GB(xb); };

    const float4* pA4 = (const float4*)(x + (size_t)b0 * (size_t)T);
    const float4* pB4 = (const float4*)(x + (size_t)b1 * (size_t)T);

    if ((T & 3) == 0 && T >= 8) {
        const int nit = T >> 2;
        float4 curA = pA4[0], curB = pB4[0];
        float4 nxtA = pA4[1], nxtB = pB4[1];
        // prologue: k=0 (B lags by the rotation), then k=1..3
        GA(curA.x); FA(); GB(curB.x);
        ROT(curA.y, curB.y); ROT(curA.z, curB.z); ROT(curA.w, curB.w);
        for (int cch = 1; cch < nit; ++cch) {
            curA = nxtA; curB = nxtB;
            const int ni = (cch + 1 < nit) ? (cch + 1) : cch;
            nxtA = pA4[ni]; nxtB = pB4[ni];          // prefetch next chunk
            ROT(curA.x, curB.x); ROT(curA.y, curB.y);
            ROT(curA.z, curB.z); ROT(curA.w, curB.w);
        }
        FB();                                        // finish k = T-1
    } else {
        // generic fallback (not hit for T=1024)
        for (int t = 0; t < T; ++t) {
            GA(x[(size_t)b0 * T + t]); FA();
            GB(x[(size_t)b1 * T + t]); FB();
        }
    }

    // logits = sum_j h_j * fc_w[j] + fc_b  (quad butterfly reduce, both chains)
    float vA = hA * fc_w[j];
    float vB = hB * fc_w[j];
    vA += hxor<1>(vA); vA += hxor<2>(vA);
    vB += hxor<1>(vB); vB += hxor<2>(vB);
    if (j == 0) {
        out[b0] = vA + fc_b[0];
        out[b1] = vB + fc_b[0];
    }
}

extern "C" void kernel_launch(void* const* d_in, const int* in_sizes, int n_in,
                              void* d_out, int out_size, void* d_ws, size_t ws_size,
                              hipStream_t stream) {
    const float* x    = (const float*)d_in[0];
    const float* W_ih = (const float*)d_in[1];
    const float* W_hh = (const float*)d_in[2];
    const float* b_ih = (const float*)d_in[3];
    const float* b_hh = (const float*)d_in[4];
    const float* fc_w = (const float*)d_in[5];
    const float* fc_b = (const float*)d_in[6];
    float* out = (float*)d_out;

    const int B = out_size;             // [B,1] logits
    const int T = in_sizes[0] / B;      // I = 1

    const int threads = 256;
    const int total = (B >> 1) * 4;     // 4 lanes per batch-PAIR
    const int grid = (total + threads - 1) / threads;
    lstm_h4sp_kernel<<<grid, threads, 0, stream>>>(x, W_ih, W_hh, b_ih, b_hh,
                                                   fc_w, fc_b, out, B, T);
}

// Round 6
// 199.459 us; speedup vs baseline: 1.0727x; 1.0727x over previous
//
#include <hip/hip_runtime.h>
#include <hip/hip_bf16.h>

#define LOG2E 1.4426950408889634f

// ---- native transcendentals (proven in rounds 2/4; R1's lib fallback was the
// regression source — never let rcp become the IEEE div sequence) ----
__device__ __forceinline__ float fexp2(float x) {
#if __has_builtin(__builtin_amdgcn_exp2f)
    return __builtin_amdgcn_exp2f(x);
#else
    float r; asm("v_exp_f32 %0, %1" : "=v"(r) : "v"(x)); return r;
#endif
}
__device__ __forceinline__ float frcp(float x) {
#if __has_builtin(__builtin_amdgcn_rcpf)
    return __builtin_amdgcn_rcpf(x);
#else
    float r; asm("v_rcp_f32 %0, %1" : "=v"(r) : "v"(x)); return r;
#endif
}

// Quad-lane XOR shuffle via DPP quad_perm (full-rate VALU).
template<int MASK>
__device__ __forceinline__ float hxor(float v) {
#if __has_builtin(__builtin_amdgcn_update_dpp)
    constexpr int ctrl = (0 ^ MASK) | ((1 ^ MASK) << 2) | ((2 ^ MASK) << 4) | ((3 ^ MASK) << 6);
    return __int_as_float(__builtin_amdgcn_update_dpp(
        0, __float_as_int(v), ctrl, 0xf, 0xf, true));
#else
    return __shfl_xor(v, MASK, 64);
#endif
}

// One lane = one (batch, hidden-unit) chain. 4 lanes per batch element.
// 131072 threads -> 2 waves/SIMD: cross-wave interleave hides the serial
// exp->rcp->exp->rcp tail that 1-wave/SIMD variants stalled on (R2: 156
// stall cyc/step). Gate order (PyTorch): i,f,g,o. exp2 scales pre-folded.
__global__ __launch_bounds__(256) void lstm_h4s2w_kernel(
    const float* __restrict__ x,
    const float* __restrict__ W_ih,   // [16]
    const float* __restrict__ W_hh,   // [16][4]
    const float* __restrict__ b_ih,   // [16]
    const float* __restrict__ b_hh,   // [16]
    const float* __restrict__ fc_w,   // [4]
    const float* __restrict__ fc_b,   // [1]
    float* __restrict__ out,          // [B]
    int B, int T)
{
    const int tid = blockIdx.x * blockDim.x + threadIdx.x;
    const int b = tid >> 2;
    const int j = tid & 3;            // hidden unit owned by this lane
    if (b >= B) return;

    const float si = -LOG2E;          // sigmoid: E = exp2(si*z) = e^-z
    const float sg = -2.0f * LOG2E;   // tanh:    E = exp2(sg*z) = e^-2z

    const int ri = j, rf = 4 + j, rg = 8 + j, ro = 12 + j;

    const float Ai = si * W_ih[ri], Ci = si * (b_ih[ri] + b_hh[ri]);
    const float Af = si * W_ih[rf], Cf = si * (b_ih[rf] + b_hh[rf]);
    const float Ag = sg * W_ih[rg], Cg = sg * (b_ih[rg] + b_hh[rg]);
    const float Ao = si * W_ih[ro], Co = si * (b_ih[ro] + b_hh[ro]);

    // Recurrent weights, permuted so index m pairs with h_{j^m}
    const float Wi0 = si * W_hh[ri*4 + (j^0)], Wi1 = si * W_hh[ri*4 + (j^1)];
    const float Wi2 = si * W_hh[ri*4 + (j^2)], Wi3 = si * W_hh[ri*4 + (j^3)];
    const float Wf0 = si * W_hh[rf*4 + (j^0)], Wf1 = si * W_hh[rf*4 + (j^1)];
    const float Wf2 = si * W_hh[rf*4 + (j^2)], Wf3 = si * W_hh[rf*4 + (j^3)];
    const float Wg0 = sg * W_hh[rg*4 + (j^0)], Wg1 = sg * W_hh[rg*4 + (j^1)];
    const float Wg2 = sg * W_hh[rg*4 + (j^2)], Wg3 = sg * W_hh[rg*4 + (j^3)];
    const float Wo0 = si * W_hh[ro*4 + (j^0)], Wo1 = si * W_hh[ro*4 + (j^1)];
    const float Wo2 = si * W_hh[ro*4 + (j^2)], Wo3 = si * W_hh[ro*4 + (j^3)];

    float h = 0.0f, c = 0.0f;

    // E* = e^{-z} (sigmoid) / e^{-2z} (tanh), p* = 1+E*:
    //   c' = [c*pi*pg + (1-Eg)*pf] * rcp(pf*pi*pg)      (1 rcp)
    //   h  = (1-Ec) * rcp(fma(Ec,po,po)), Ec = exp2(sg*c')  (1 rcp)
    // (1-E)*q folded as fmaf(-E,q,q) — scalar neg modifiers are free.
    auto STEP = [&](float xv) {
        const float h1 = hxor<1>(h);
        const float h2 = hxor<2>(h);
        const float h3 = hxor<3>(h);
        const float zi = fmaf(Wi1, h1, fmaf(Wi0, h, fmaf(Ai, xv, Ci)))
                       + fmaf(Wi3, h3, Wi2 * h2);
        const float zf = fmaf(Wf1, h1, fmaf(Wf0, h, fmaf(Af, xv, Cf)))
                       + fmaf(Wf3, h3, Wf2 * h2);
        const float zg = fmaf(Wg1, h1, fmaf(Wg0, h, fmaf(Ag, xv, Cg)))
                       + fmaf(Wg3, h3, Wg2 * h2);
        const float zo = fmaf(Wo1, h1, fmaf(Wo0, h, fmaf(Ao, xv, Co)))
                       + fmaf(Wo3, h3, Wo2 * h2);
        const float Ei = fexp2(zi);
        const float Ef = fexp2(zf);
        const float Eg = fexp2(zg);
        const float Eo = fexp2(zo);
        const float pi_ = 1.0f + Ei, pf_ = 1.0f + Ef;
        const float pg_ = 1.0f + Eg, po_ = 1.0f + Eo;
        const float t1  = pi_ * pg_;
        const float u   = fmaf(-Eg, pf_, pf_);      // (1-Eg)*pf
        const float num = fmaf(c, t1, u);
        const float den = t1 * pf_;
        const float r   = frcp(den);
        const float sn  = sg * num;                 // in rcp's shadow
        c = num * r;
        const float Ec  = fexp2(sn * r);            // exp2(sg*c')
        const float d2  = fmaf(Ec, po_, po_);       // po*(1+Ec)
        const float r2  = frcp(d2);
        h = fmaf(-Ec, r2, r2);                      // (1-Ec)*rcp(...)
    };

    const float4* xv4 = (const float4*)(x + (size_t)b * (size_t)T);
    const int nch = T >> 2;
    float4 cur = xv4[0];
    for (int ch = 0; ch < nch; ++ch) {
        const int ni = ((ch + 1) < nch) ? (ch + 1) : ch;
        float4 nxt = xv4[ni];           // prefetch next chunk before compute
        STEP(cur.x); STEP(cur.y); STEP(cur.z); STEP(cur.w);
        cur = nxt;
    }
    for (int t = nch << 2; t < T; ++t)   // tail, not hit for T=1024
        STEP(x[(size_t)b * T + t]);

    // logits[b] = sum_j h_j * fc_w[j] + fc_b  (quad butterfly reduce)
    float v = h * fc_w[j];
    v += hxor<1>(v);
    v += hxor<2>(v);
    if (j == 0) out[b] = v + fc_b[0];
}

extern "C" void kernel_launch(void* const* d_in, const int* in_sizes, int n_in,
                              void* d_out, int out_size, void* d_ws, size_t ws_size,
                              hipStream_t stream) {
    const float* x    = (const float*)d_in[0];
    const float* W_ih = (const float*)d_in[1];
    const float* W_hh = (const float*)d_in[2];
    const float* b_ih = (const float*)d_in[3];
    const float* b_hh = (const float*)d_in[4];
    const float* fc_w = (const float*)d_in[5];
    const float* fc_b = (const float*)d_in[6];
    float* out = (float*)d_out;

    const int B = out_size;             // [B,1] logits
    const int T = in_sizes[0] / B;      // I = 1

    const int threads = 256;
    const int total = B * 4;            // 4 lanes per batch element
    const int grid = (total + threads - 1) / threads;
    lstm_h4s2w_kernel<<<grid, threads, 0, stream>>>(x, W_ih, W_hh, b_ih, b_hh,
                                                    fc_w, fc_b, out, B, T);
}

// Round 7
// 183.955 us; speedup vs baseline: 1.1631x; 1.0843x over previous
//
#include <hip/hip_runtime.h>
#include <hip/hip_bf16.h>

#define LOG2E 1.4426950408889634f

// ---- native transcendentals ----
__device__ __forceinline__ float fexp2(float x) {
#if __has_builtin(__builtin_amdgcn_exp2f)
    return __builtin_amdgcn_exp2f(x);
#else
    float r; asm("v_exp_f32 %0, %1" : "=v"(r) : "v"(x)); return r;
#endif
}
__device__ __forceinline__ float frcp(float x) {
#if __has_builtin(__builtin_amdgcn_rcpf)
    return __builtin_amdgcn_rcpf(x);
#else
    float r; asm("v_rcp_f32 %0, %1" : "=v"(r) : "v"(x)); return r;
#endif
}

// Quad-lane XOR shuffle via DPP quad_perm (full-rate VALU).
template<int MASK>
__device__ __forceinline__ float hxor(float v) {
#if __has_builtin(__builtin_amdgcn_update_dpp)
    constexpr int ctrl = (0 ^ MASK) | ((1 ^ MASK) << 2) | ((2 ^ MASK) << 4) | ((3 ^ MASK) << 6);
    return __int_as_float(__builtin_amdgcn_update_dpp(
        0, __float_as_int(v), ctrl, 0xf, 0xf, true));
#else
    return __shfl_xor(v, MASK, 64);
#endif
}

// One lane = hidden unit j of TWO batch elements (b0=p, b1=p+B/2) as two
// PURE-SCALAR chains interleaved statement-by-statement in one basic block:
//   zA -> expA -> zB (hides expA) -> expB -> tailA (hides expB)
//   -> tailB (hides tailA rcp) -> next zA (hides tailB).
// 65536 threads = 1 wave/SIMD; ILP (not TLP) hides the trans tail — measured
// best (R2 13.5 cyc/batch-step vs R6 2-wave 18.0).
// Gate order (PyTorch): i,f,g,o. exp2 scales pre-folded into weights/biases.
__global__ __launch_bounds__(256, 1) void lstm_h4si_kernel(
    const float* __restrict__ x,
    const float* __restrict__ W_ih,   // [16]
    const float* __restrict__ W_hh,   // [16][4]
    const float* __restrict__ b_ih,   // [16]
    const float* __restrict__ b_hh,   // [16]
    const float* __restrict__ fc_w,   // [4]
    const float* __restrict__ fc_b,   // [1]
    float* __restrict__ out,          // [B]
    int B, int T)
{
    const int tid  = blockIdx.x * blockDim.x + threadIdx.x;
    const int half = B >> 1;
    const int p = tid >> 2;          // batch-pair index
    const int j = tid & 3;           // hidden unit owned by this lane
    if (p >= half) return;
    const int b0 = p, b1 = p + half;

    const float si = -LOG2E;          // sigmoid: E = exp2(si*z) = e^-z
    const float sg = -2.0f * LOG2E;   // tanh:    E = exp2(sg*z) = e^-2z

    const int ri = j, rf = 4 + j, rg = 8 + j, ro = 12 + j;

    const float Ai = si * W_ih[ri], Ci = si * (b_ih[ri] + b_hh[ri]);
    const float Af = si * W_ih[rf], Cf = si * (b_ih[rf] + b_hh[rf]);
    const float Ag = sg * W_ih[rg], Cg = sg * (b_ih[rg] + b_hh[rg]);
    const float Ao = si * W_ih[ro], Co = si * (b_ih[ro] + b_hh[ro]);

    // Recurrent weights, permuted so index m pairs with h_{j^m}
    const float Wi0 = si * W_hh[ri*4 + (j^0)], Wi1 = si * W_hh[ri*4 + (j^1)];
    const float Wi2 = si * W_hh[ri*4 + (j^2)], Wi3 = si * W_hh[ri*4 + (j^3)];
    const float Wf0 = si * W_hh[rf*4 + (j^0)], Wf1 = si * W_hh[rf*4 + (j^1)];
    const float Wf2 = si * W_hh[rf*4 + (j^2)], Wf3 = si * W_hh[rf*4 + (j^3)];
    const float Wg0 = sg * W_hh[rg*4 + (j^0)], Wg1 = sg * W_hh[rg*4 + (j^1)];
    const float Wg2 = sg * W_hh[rg*4 + (j^2)], Wg3 = sg * W_hh[rg*4 + (j^3)];
    const float Wo0 = si * W_hh[ro*4 + (j^0)], Wo1 = si * W_hh[ro*4 + (j^1)];
    const float Wo2 = si * W_hh[ro*4 + (j^2)], Wo3 = si * W_hh[ro*4 + (j^3)];

    float hA = 0.0f, cA = 0.0f;
    float hB = 0.0f, cB = 0.0f;

    // E* = e^{-z} (sigmoid) / e^{-2z} (tanh), p* = 1+E*:
    //   c' = [c*pi*pg + (1-Eg)*pf] * rcp(pf*pi*pg)          (1 rcp)
    //   h  = (1-Ec) * rcp(fma(Ec,po,po)), Ec = exp2(sg*c')  (1 rcp)
    auto STEP2 = [&](float xa, float xb) {
        // --- shuffles, both chains (independent, fills DPP latency) ---
        const float a1 = hxor<1>(hA), b1 = hxor<1>(hB);
        const float a2 = hxor<2>(hA), b2 = hxor<2>(hB);
        const float a3 = hxor<3>(hA), b3 = hxor<3>(hB);
        // --- chain A gate dots ---
        const float ziA = fmaf(Wi1, a1, fmaf(Wi0, hA, fmaf(Ai, xa, Ci)))
                        + fmaf(Wi3, a3, Wi2 * a2);
        const float zfA = fmaf(Wf1, a1, fmaf(Wf0, hA, fmaf(Af, xa, Cf)))
                        + fmaf(Wf3, a3, Wf2 * a2);
        const float zgA = fmaf(Wg1, a1, fmaf(Wg0, hA, fmaf(Ag, xa, Cg)))
                        + fmaf(Wg3, a3, Wg2 * a2);
        const float zoA = fmaf(Wo1, a1, fmaf(Wo0, hA, fmaf(Ao, xa, Co)))
                        + fmaf(Wo3, a3, Wo2 * a2);
        // --- chain A exps ---
        const float EiA = fexp2(ziA);
        const float EfA = fexp2(zfA);
        const float EgA = fexp2(zgA);
        const float EoA = fexp2(zoA);
        // --- chain B gate dots (hides A's exp latency) ---
        const float ziB = fmaf(Wi1, b1, fmaf(Wi0, hB, fmaf(Ai, xb, Ci)))
                        + fmaf(Wi3, b3, Wi2 * b2);
        const float zfB = fmaf(Wf1, b1, fmaf(Wf0, hB, fmaf(Af, xb, Cf)))
                        + fmaf(Wf3, b3, Wf2 * b2);
        const float zgB = fmaf(Wg1, b1, fmaf(Wg0, hB, fmaf(Ag, xb, Cg)))
                        + fmaf(Wg3, b3, Wg2 * b2);
        const float zoB = fmaf(Wo1, b1, fmaf(Wo0, hB, fmaf(Ao, xb, Co)))
                        + fmaf(Wo3, b3, Wo2 * b2);
        // --- chain B exps ---
        const float EiB = fexp2(ziB);
        const float EfB = fexp2(zfB);
        const float EgB = fexp2(zgB);
        const float EoB = fexp2(zoB);
        // --- chain A tail (hides B's exp latency) ---
        const float piA = 1.0f + EiA, pfA = 1.0f + EfA;
        const float pgA = 1.0f + EgA, poA = 1.0f + EoA;
        const float t1A  = piA * pgA;
        const float uA   = fmaf(-EgA, pfA, pfA);      // (1-Eg)*pf
        const float numA = fmaf(cA, t1A, uA);
        const float denA = t1A * pfA;
        const float rA   = frcp(denA);
        const float snA  = sg * numA;                 // off critical path
        cA = numA * rA;
        const float EcA  = fexp2(snA * rA);           // exp2(sg*c')
        const float d2A  = fmaf(EcA, poA, poA);       // po*(1+Ec)
        const float r2A  = frcp(d2A);
        // --- chain B tail (hides A's rcp/exp latency) ---
        const float piB = 1.0f + EiB, pfB = 1.0f + EfB;
        const float pgB = 1.0f + EgB, poB = 1.0f + EoB;
        const float t1B  = piB * pgB;
        const float uB   = fmaf(-EgB, pfB, pfB);
        const float numB = fmaf(cB, t1B, uB);
        const float denB = t1B * pfB;
        const float rB   = frcp(denB);
        const float snB  = sg * numB;
        cB = numB * rB;
        const float EcB  = fexp2(snB * rB);
        const float d2B  = fmaf(EcB, poB, poB);
        const float r2B  = frcp(d2B);
        // --- finishes ---
        hA = fmaf(-EcA, r2A, r2A);                    // (1-Ec)*rcp(...)
        hB = fmaf(-EcB, r2B, r2B);
    };

    const float4* p0 = (const float4*)(x + (size_t)b0 * (size_t)T);
    const float4* p1 = (const float4*)(x + (size_t)b1 * (size_t)T);
    const int nit = T >> 3;           // 8 steps per iteration
    float4 a0 = p0[0], a1 = p0[1];
    float4 c0 = p1[0], c1 = p1[1];
    for (int it = 0; it < nit; ++it) {
        const int ni = ((it + 1) < nit) ? (it + 1) : it;
        float4 na0 = p0[2*ni], na1 = p0[2*ni + 1];    // prefetch 8 steps ahead
        float4 nc0 = p1[2*ni], nc1 = p1[2*ni + 1];
        STEP2(a0.x, c0.x); STEP2(a0.y, c0.y);
        STEP2(a0.z, c0.z); STEP2(a0.w, c0.w);
        STEP2(a1.x, c1.x); STEP2(a1.y, c1.y);
        STEP2(a1.z, c1.z); STEP2(a1.w, c1.w);
        a0 = na0; a1 = na1; c0 = nc0; c1 = nc1;
    }
    for (int t = nit << 3; t < T; ++t)   // tail, not hit for T=1024
        STEP2(x[(size_t)b0 * T + t], x[(size_t)b1 * T + t]);

    // logits = sum_j h_j * fc_w[j] + fc_b  (quad butterfly reduce, both chains)
    float vA = hA * fc_w[j];
    float vB = hB * fc_w[j];
    vA += hxor<1>(vA); vB += hxor<1>(vB);
    vA += hxor<2>(vA); vB += hxor<2>(vB);
    if (j == 0) {
        out[b0] = vA + fc_b[0];
        out[b1] = vB + fc_b[0];
    }
}

extern "C" void kernel_launch(void* const* d_in, const int* in_sizes, int n_in,
                              void* d_out, int out_size, void* d_ws, size_t ws_size,
                              hipStream_t stream) {
    const float* x    = (const float*)d_in[0];
    const float* W_ih = (const float*)d_in[1];
    const float* W_hh = (const float*)d_in[2];
    const float* b_ih = (const float*)d_in[3];
    const float* b_hh = (const float*)d_in[4];
    const float* fc_w = (const float*)d_in[5];
    const float* fc_b = (const float*)d_in[6];
    float* out = (float*)d_out;

    const int B = out_size;             // [B,1] logits
    const int T = in_sizes[0] / B;      // I = 1

    const int threads = 256;
    const int total = (B >> 1) * 4;     // 4 lanes per batch-PAIR
    const int grid = (total + threads - 1) / threads;
    lstm_h4si_kernel<<<grid, threads, 0, stream>>>(x, W_ih, W_hh, b_ih, b_hh,
                                                   fc_w, fc_b, out, B, T);
}

// Round 8
// 158.837 us; speedup vs baseline: 1.3470x; 1.1581x over previous
//
#include <hip/hip_runtime.h>
#include <hip/hip_bf16.h>

#define LOG2E 1.4426950408889634f

typedef float f32x2 __attribute__((ext_vector_type(2)));

// ---- native transcendentals (never fall back to lib exp2f / IEEE divide) ----
__device__ __forceinline__ float fexp2(float x) {
#if __has_builtin(__builtin_amdgcn_exp2f)
    return __builtin_amdgcn_exp2f(x);
#else
    float r; asm("v_exp_f32 %0, %1" : "=v"(r) : "v"(x)); return r;
#endif
}
__device__ __forceinline__ float frcp(float x) {
#if __has_builtin(__builtin_amdgcn_rcpf)
    return __builtin_amdgcn_rcpf(x);
#else
    float r; asm("v_rcp_f32 %0, %1" : "=v"(r) : "v"(x)); return r;
#endif
}
__device__ __forceinline__ f32x2 vexp2(f32x2 x) { f32x2 r; r.x = fexp2(x.x); r.y = fexp2(x.y); return r; }
__device__ __forceinline__ f32x2 vrcp (f32x2 x) { f32x2 r; r.x = frcp(x.x); r.y = frcp(x.y); return r; }

// packed fma intrinsic form: lowers scalar on this toolchain, but produces the
// leanest codegen measured (busy 277 cyc/step-pair vs 371-403 for all
// hand-scheduled scalar variants, R4/R6/R7). Keep exactly as-is.
__device__ __forceinline__ f32x2 pk_fma(f32x2 a, f32x2 b, f32x2 c) {
#if __has_builtin(__builtin_elementwise_fma)
    return __builtin_elementwise_fma(a, b, c);
#else
    f32x2 r; r.x = fmaf(a.x, b.x, c.x); r.y = fmaf(a.y, b.y, c.y); return r;
#endif
}
__device__ __forceinline__ f32x2 sp(float v) { return (f32x2){v, v}; }

// Quad-lane XOR shuffle via DPP quad_perm (full-rate VALU, no LDS pipe).
template<int MASK>
__device__ __forceinline__ float hxor(float v) {
#if __has_builtin(__builtin_amdgcn_update_dpp)
    constexpr int ctrl = (0 ^ MASK) | ((1 ^ MASK) << 2) | ((2 ^ MASK) << 4) | ((3 ^ MASK) << 6);
    return __int_as_float(__builtin_amdgcn_update_dpp(
        0, __float_as_int(v), ctrl, 0xf, 0xf, true));
#else
    return __shfl_xor(v, MASK, 64);
#endif
}
template<int MASK>
__device__ __forceinline__ f32x2 hxor2(f32x2 v) {
    f32x2 r; r.x = hxor<MASK>(v.x); r.y = hxor<MASK>(v.y); return r;
}

// One lane = hidden unit j of TWO batch elements (b, b + B/2), packed in f32x2.
// 4 lanes (a quad) per batch-pair. Gate order (PyTorch): i,f,g,o.
// exp2 scale factors pre-folded into weights/biases.
__global__ __launch_bounds__(256, 1) void lstm_h4x2_kernel(
    const float* __restrict__ x,
    const float* __restrict__ W_ih,   // [16]
    const float* __restrict__ W_hh,   // [16][4]
    const float* __restrict__ b_ih,   // [16]
    const float* __restrict__ b_hh,   // [16]
    const float* __restrict__ fc_w,   // [4]
    const float* __restrict__ fc_b,   // [1]
    float* __restrict__ out,          // [B]
    int B, int T)
{
    const int tid  = blockIdx.x * blockDim.x + threadIdx.x;
    const int half = B >> 1;
    const int p = tid >> 2;          // batch-pair index
    const int j = tid & 3;           // hidden unit owned by this lane
    if (p >= half) return;
    const int b0 = p, b1 = p + half;

    const float si = -LOG2E;          // sigmoid: E = exp2(si*z) = e^-z
    const float sg = -2.0f * LOG2E;   // tanh:    E = exp2(sg*z) = e^-2z

    const int ri = j, rf = 4 + j, rg = 8 + j, ro = 12 + j;

    // x-path coefficients (I=1): arg_G = A_G * x_t + C_G + sum W h
    const float Ai = si * W_ih[ri], Ci = si * (b_ih[ri] + b_hh[ri]);
    const float Af = si * W_ih[rf], Cf = si * (b_ih[rf] + b_hh[rf]);
    const float Ag = sg * W_ih[rg], Cg = sg * (b_ih[rg] + b_hh[rg]);
    const float Ao = si * W_ih[ro], Co = si * (b_ih[ro] + b_hh[ro]);

    // Recurrent weights, permuted so index m pairs with h_{j^m}
    const float Wi0 = si * W_hh[ri*4 + (j^0)], Wi1 = si * W_hh[ri*4 + (j^1)];
    const float Wi2 = si * W_hh[ri*4 + (j^2)], Wi3 = si * W_hh[ri*4 + (j^3)];
    const float Wf0 = si * W_hh[rf*4 + (j^0)], Wf1 = si * W_hh[rf*4 + (j^1)];
    const float Wf2 = si * W_hh[rf*4 + (j^2)], Wf3 = si * W_hh[rf*4 + (j^3)];
    const float Wg0 = sg * W_hh[rg*4 + (j^0)], Wg1 = sg * W_hh[rg*4 + (j^1)];
    const float Wg2 = sg * W_hh[rg*4 + (j^2)], Wg3 = sg * W_hh[rg*4 + (j^3)];
    const float Wo0 = si * W_hh[ro*4 + (j^0)], Wo1 = si * W_hh[ro*4 + (j^1)];
    const float Wo2 = si * W_hh[ro*4 + (j^2)], Wo3 = si * W_hh[ro*4 + (j^3)];

    f32x2 h = sp(0.0f), c = sp(0.0f);

    // With E* = e^{-z} (sigmoid) / e^{-2z} (tanh), p* = 1+E*:
    //   c' = [c*pi*pg + (1-Eg)*pf] / (pf*pi*pg)          (1 rcp)
    //   h  = (1-Ec) * rcp(po*(1+Ec)),  Ec = e^{-2 c'}    (1 rcp)
    // (1-E)*q folded as fma(-E, q, q).
    auto STEP = [&](f32x2 xv) {
        const f32x2 h1 = hxor2<1>(h);
        const f32x2 h2 = hxor2<2>(h);
        const f32x2 h3 = hxor2<3>(h);
        f32x2 ai = pk_fma(sp(Ai), xv, sp(Ci));
        f32x2 af = pk_fma(sp(Af), xv, sp(Cf));
        f32x2 ag = pk_fma(sp(Ag), xv, sp(Cg));
        f32x2 ao = pk_fma(sp(Ao), xv, sp(Co));
        ai = pk_fma(sp(Wi0), h, ai); ai = pk_fma(sp(Wi1), h1, ai);
        ai = pk_fma(sp(Wi2), h2, ai); ai = pk_fma(sp(Wi3), h3, ai);
        af = pk_fma(sp(Wf0), h, af); af = pk_fma(sp(Wf1), h1, af);
        af = pk_fma(sp(Wf2), h2, af); af = pk_fma(sp(Wf3), h3, af);
        ag = pk_fma(sp(Wg0), h, ag); ag = pk_fma(sp(Wg1), h1, ag);
        ag = pk_fma(sp(Wg2), h2, ag); ag = pk_fma(sp(Wg3), h3, ag);
        ao = pk_fma(sp(Wo0), h, ao); ao = pk_fma(sp(Wo1), h1, ao);
        ao = pk_fma(sp(Wo2), h2, ao); ao = pk_fma(sp(Wo3), h3, ao);
        const f32x2 Ei = vexp2(ai);
        const f32x2 Ef = vexp2(af);
        const f32x2 Eg = vexp2(ag);
        const f32x2 Eo = vexp2(ao);
        const f32x2 pi_ = sp(1.0f) + Ei, pf_ = sp(1.0f) + Ef;
        const f32x2 pg_ = sp(1.0f) + Eg, po_ = sp(1.0f) + Eo;
        const f32x2 t1  = pi_ * pg_;
        const f32x2 u   = pk_fma(-Eg, pf_, pf_);      // (1-Eg)*pf
        const f32x2 num = pk_fma(c, t1, u);
        const f32x2 den = t1 * pf_;
        const f32x2 sn  = sp(sg) * num;               // in rcp's shadow
        const f32x2 r   = vrcp(den);
        c = num * r;
        const f32x2 Ec  = vexp2(sn * r);              // exp2(sg*c')
        const f32x2 d2  = pk_fma(Ec, po_, po_);       // po*(1+Ec)
        const f32x2 r2  = vrcp(d2);
        h = pk_fma(-Ec, r2, r2);                      // (1-Ec)*rcp(...)
    };

    const float4* p0 = (const float4*)(x + (size_t)b0 * (size_t)T);
    const float4* p1 = (const float4*)(x + (size_t)b1 * (size_t)T);
    const int nit = T >> 3;           // 8 steps per iteration
    float4 a0 = p0[0], a1 = p0[1];
    float4 c0 = p1[0], c1 = p1[1];
    for (int it = 0; it < nit; ++it) {
        const int ni = ((it + 1) < nit) ? (it + 1) : it;
        float4 na0 = p0[2*ni], na1 = p0[2*ni + 1];    // prefetch 8 steps ahead
        float4 nc0 = p1[2*ni], nc1 = p1[2*ni + 1];
        STEP((f32x2){a0.x, c0.x}); STEP((f32x2){a0.y, c0.y});
        STEP((f32x2){a0.z, c0.z}); STEP((f32x2){a0.w, c0.w});
        STEP((f32x2){a1.x, c1.x}); STEP((f32x2){a1.y, c1.y});
        STEP((f32x2){a1.z, c1.z}); STEP((f32x2){a1.w, c1.w});
        a0 = na0; a1 = na1; c0 = nc0; c1 = nc1;
    }
    for (int t = nit << 3; t < T; ++t)   // tail, not hit for T=1024
        STEP((f32x2){x[(size_t)b0 * T + t], x[(size_t)b1 * T + t]});

    // logits = sum_j h_j * fc_w[j] + fc_b  (quad butterfly reduce, both chains)
    f32x2 v = h * sp(fc_w[j]);
    v = v + hxor2<1>(v);
    v = v + hxor2<2>(v);
    if (j == 0) {
        out[b0] = v.x + fc_b[0];
        out[b1] = v.y + fc_b[0];
    }
}

extern "C" void kernel_launch(void* const* d_in, const int* in_sizes, int n_in,
                              void* d_out, int out_size, void* d_ws, size_t ws_size,
                              hipStream_t stream) {
    const float* x    = (const float*)d_in[0];
    const float* W_ih = (const float*)d_in[1];
    const float* W_hh = (const float*)d_in[2];
    const float* b_ih = (const float*)d_in[3];
    const float* b_hh = (const float*)d_in[4];
    const float* fc_w = (const float*)d_in[5];
    const float* fc_b = (const float*)d_in[6];
    float* out = (float*)d_out;

    const int B = out_size;             // [B,1] logits
    const int T = in_sizes[0] / B;      // I = 1

    const int threads = 256;
    const int total = (B >> 1) * 4;     // 4 lanes per batch-PAIR
    const int grid = (total + threads - 1) / threads;
    lstm_h4x2_kernel<<<grid, threads, 0, stream>>>(x, W_ih, W_hh, b_ih, b_hh,
                                                   fc_w, fc_b, out, B, T);
}